// Round 3
// baseline (365.579 us; speedup 1.0000x reference)
//
#include <hip/hip_runtime.h>

// LSTM, B=4096, T=2048, IN=3, H=4. 16 lanes per batch element; each 16-lane
// group now carries TWO independent batch elements (R=2), instruction-
// interleaved so each chain's dependency stalls are filled by the other
// chain's issue. lane l = 4q+j: gate q (i,f,g,o), unit j; every lane computes
// the full recurrence for unit j via DPP quad_perm / row_ror (VALU pipe).
// 128 blocks x 256 thr = 512 waves (0.5/SIMD) - latency, not occupancy, is
// the binding resource. Activation slope m is pre-folded into w_ih/w_hh.

static constexpr int T_STEPS = 2048;
static constexpr int CHUNK   = 8;               // timesteps per x-staging chunk
static constexpr int NCHUNK  = T_STEPS / CHUNK; // 256

template<int CTRL>
__device__ __forceinline__ float dpp_f(float v) {
    return __int_as_float(__builtin_amdgcn_update_dpp(
        0, __float_as_int(v), CTRL, 0xF, 0xF, false));
}

struct Ctx {
    float wih0, wih1, wih2;        // pre-scaled by per-lane m
    float whh0, whh1, whh2, whh3;  // pre-scaled by per-lane m
    float Aa, Bb;                  // act = Aa * rcp(1+exp2(gp_scaled)) + Bb
    bool  b0, b1fo;                // gate-quadrant mux bits (b1fo absorbs DPP dir)
};

template<int J>
__device__ __forceinline__ float comp(const float4& v) {
    if constexpr (J == 0) return v.x;
    else if constexpr (J == 1) return v.y;
    else if constexpr (J == 2) return v.z;
    else return v.w;
}

// xp[TT] = m * (w_ih . x_t) for the 8 steps of a staged chunk (off-chain)
template<int TT>
__device__ __forceinline__ void projx8(float (&xp)[CHUNK], const float4 (&bf)[6],
                                       const Ctx& k) {
    constexpr int j0 = 3 * TT, j1 = j0 + 1, j2 = j0 + 2;
    float x0 = comp<(j0 & 3)>(bf[j0 >> 2]);
    float x1 = comp<(j1 & 3)>(bf[j1 >> 2]);
    float x2 = comp<(j2 & 3)>(bf[j2 >> 2]);
    xp[TT] = fmaf(x0, k.wih0, fmaf(x1, k.wih1, x2 * k.wih2));
    if constexpr (TT + 1 < CHUNK) projx8<TT + 1>(xp, bf, k);
}

__device__ __forceinline__ void lstm_step(float xp, float& h, float& c, const Ctx& k) {
    float hb0 = dpp_f<0x00>(h);   // quad_perm broadcasts of h0..h3
    float hb1 = dpp_f<0x55>(h);
    float hb2 = dpp_f<0xAA>(h);
    float hb3 = dpp_f<0xFF>(h);

    // pre-activation, already scaled by m (weights pre-folded)
    float p0 = fmaf(hb1, k.whh1, fmaf(hb0, k.whh0, xp));
    float p1 = fmaf(hb2, k.whh2, hb3 * k.whh3);
    float gp = p0 + p1;

    float e   = __builtin_amdgcn_exp2f(gp);
    float act = fmaf(k.Aa, __builtin_amdgcn_rcpf(1.0f + e), k.Bb);

    float t1 = dpp_f<0x124>(act);   // row_ror:4
    float t2 = dpp_f<0x128>(act);   // row_ror:8
    float t3 = dpp_f<0x12C>(act);   // row_ror:12
    float prod = k.b0 ? t1 * t3 : act * t2;   // i*g (direction-invariant)
    float A  = k.b0 ? t2  : t1;
    float Bv = k.b0 ? act : t3;
    float f  = k.b1fo ? A : Bv;
    float o  = k.b1fo ? Bv : A;

    float cn = fmaf(f, c, prod);
    c = cn;
    float e2 = __builtin_amdgcn_exp2f(-2.885390081777927f * cn);
    float th = fmaf(2.0f, __builtin_amdgcn_rcpf(1.0f + e2), -1.0f);
    h = o * th;
}

// two independent chains, interleaved per step so the scheduler fills stalls
template<int TT>
__device__ __forceinline__ void steps2(const float (&xpA)[CHUNK], const float (&xpB)[CHUNK],
                                       float& hA, float& cA, float& hB, float& cB,
                                       const Ctx& k) {
    lstm_step(xpA[TT], hA, cA, k);
    lstm_step(xpB[TT], hB, cB, k);
    if constexpr (TT + 1 < CHUNK) steps2<TT + 1>(xpA, xpB, hA, cA, hB, cB, k);
}

__device__ __forceinline__ void loadbf6(float4 (&bf)[6], const float4* p) {
    #pragma unroll
    for (int i = 0; i < 6; ++i) bf[i] = p[i];
}

__global__ __launch_bounds__(256, 1) void lstm_kernel(
    const float* __restrict__ x,
    const float* __restrict__ w_ih,
    const float* __restrict__ w_hh,
    const float* __restrict__ fc_w,
    const float* __restrict__ fc_b,
    float* __restrict__ out)
{
    const int tid = threadIdx.x;
    const int l16 = tid & 15;
    const int pr  = blockIdx.x * 16 + (tid >> 4);  // pair index 0..2047
    const int b0  = 2 * pr, b1 = 2 * pr + 1;
    const int gt  = l16 >> 2;

    const bool is_g = (gt == 2);
    const float mm  = is_g ? -2.885390081777927f : -1.4426950408889634f;

    Ctx k;
    k.wih0 = mm * w_ih[l16 * 3 + 0];
    k.wih1 = mm * w_ih[l16 * 3 + 1];
    k.wih2 = mm * w_ih[l16 * 3 + 2];
    k.whh0 = mm * w_hh[l16 * 4 + 0];
    k.whh1 = mm * w_hh[l16 * 4 + 1];
    k.whh2 = mm * w_hh[l16 * 4 + 2];
    k.whh3 = mm * w_hh[l16 * 4 + 3];
    k.Aa = is_g ? 2.0f : 1.0f;
    k.Bb = is_g ? -1.0f : 0.0f;
    k.b0 = (gt & 1) != 0;
    {   // runtime probe for row_ror direction; folds into the f/o mux bit
        float probe = (float)l16;
        float t1p = dpp_f<0x124>(probe);
        bool dirB = (t1p == (float)((l16 + 4) & 15));
        k.b1fo = (((gt & 2) != 0) != dirB);
    }

    const float4* xA = reinterpret_cast<const float4*>(x + (size_t)b0 * (T_STEPS * 3));
    const float4* xB = reinterpret_cast<const float4*>(x + (size_t)b1 * (T_STEPS * 3));

    float4 bfA0[6], bfA1[6], bfB0[6], bfB1[6];
    float  xpA0[CHUNK], xpA1[CHUNK], xpB0[CHUNK], xpB1[CHUNK];

    loadbf6(bfA0, xA);      loadbf6(bfA1, xB);
    loadbf6(bfB0, xA + 6);  loadbf6(bfB1, xB + 6);
    projx8<0>(xpA0, bfA0, k);
    projx8<0>(xpA1, bfA1, k);

    float hA = 0.f, cA = 0.f, hB = 0.f, cB = 0.f;

    for (int it = 0; it < NCHUNK / 2; ++it) {
        const int ca = (2 * it + 2 < NCHUNK) ? 2 * it + 2 : NCHUNK - 1;
        loadbf6(bfA0, xA + ca * 6);
        loadbf6(bfA1, xB + ca * 6);
        projx8<0>(xpB0, bfB0, k);
        projx8<0>(xpB1, bfB1, k);
        steps2<0>(xpA0, xpA1, hA, cA, hB, cB, k);

        const int cb = (2 * it + 3 < NCHUNK) ? 2 * it + 3 : NCHUNK - 1;
        loadbf6(bfB0, xA + cb * 6);
        loadbf6(bfB1, xB + cb * 6);
        projx8<0>(xpA0, bfA0, k);
        projx8<0>(xpA1, bfA1, k);
        steps2<0>(xpB0, xpB1, hA, cA, hB, cB, k);
    }

    // out[b] = fc_w . h + fc_b ; lane 4m+j holds h_j -> quad reduce
    const float fw = fc_w[l16 & 3];
    float rA = hA * fw;
    rA += dpp_f<0xB1>(rA);
    rA += dpp_f<0x4E>(rA);
    float rB = hB * fw;
    rB += dpp_f<0xB1>(rB);
    rB += dpp_f<0x4E>(rB);
    if (l16 == 0) {
        const float fcb = fc_b[0];
        out[b0] = rA + fcb;
        out[b1] = rB + fcb;
    }
}

extern "C" void kernel_launch(void* const* d_in, const int* in_sizes, int n_in,
                              void* d_out, int out_size, void* d_ws, size_t ws_size,
                              hipStream_t stream) {
    const float* x    = (const float*)d_in[0];
    const float* w_ih = (const float*)d_in[1];
    const float* w_hh = (const float*)d_in[2];
    const float* fc_w = (const float*)d_in[3];
    const float* fc_b = (const float*)d_in[4];
    float* out = (float*)d_out;

    dim3 grid(4096 / 32);   // 128 blocks: 16 groups/block x 2 elems/group
    dim3 block(256);
    hipLaunchKernelGGL(lstm_kernel, grid, block, 0, stream,
                       x, w_ih, w_hh, fc_w, fc_b, out);
}

// Round 4
// 339.389 us; speedup vs baseline: 1.0772x; 1.0772x over previous
//
#include <hip/hip_runtime.h>

// LSTM, B=4096, T=2048, IN=3, H=4. 16 lanes per batch element, 2 elements per
// 16-lane group (R=2), with the two chains' per-stage instructions FORCED to
// interleave via sched_barrier(0) walls: the in-order wave pays each
// exp2/rcp dependency stall once per PAIR of chains instead of once each.
// wall = T * max(L, 2I)/2 ~= T * 120cy. 128 blocks x 256 thr = 512 waves.
// R3 lesson: without the walls the compiler serializes the chains (VALUBusy
// halved, zero overlap). DPP quad_perm/row_ror carries all cross-lane moves.

static constexpr int T_STEPS = 2048;
static constexpr int CHUNK   = 8;               // timesteps per x-staging chunk
static constexpr int NCHUNK  = T_STEPS / CHUNK; // 256

__device__ __forceinline__ void sb() { __builtin_amdgcn_sched_barrier(0); }

template<int CTRL>
__device__ __forceinline__ float dpp_f(float v) {
    return __int_as_float(__builtin_amdgcn_update_dpp(
        0, __float_as_int(v), CTRL, 0xF, 0xF, false));
}

struct Ctx {
    float wih0, wih1, wih2;        // pre-scaled by per-lane m
    float whh0, whh1, whh2, whh3;  // pre-scaled by per-lane m
    float Aa, Bb;                  // act = Aa * rcp(1+exp2(gp)) + Bb
    bool  b0, b1fo;                // gate-quadrant mux bits (b1fo absorbs DPP dir)
};

struct St { float h, c; };

template<int J>
__device__ __forceinline__ float comp(const float4& v) {
    if constexpr (J == 0) return v.x;
    else if constexpr (J == 1) return v.y;
    else if constexpr (J == 2) return v.z;
    else return v.w;
}

template<int TT>
__device__ __forceinline__ void projx8(float (&xp)[CHUNK], const float4 (&bf)[6],
                                       const Ctx& k) {
    constexpr int j0 = 3 * TT, j1 = j0 + 1, j2 = j0 + 2;
    float x0 = comp<(j0 & 3)>(bf[j0 >> 2]);
    float x1 = comp<(j1 & 3)>(bf[j1 >> 2]);
    float x2 = comp<(j2 & 3)>(bf[j2 >> 2]);
    xp[TT] = fmaf(x0, k.wih0, fmaf(x1, k.wih1, x2 * k.wih2));
    if constexpr (TT + 1 < CHUNK) projx8<TT + 1>(xp, bf, k);
}

// One timestep for BOTH chains, stage-interleaved and pinned with
// sched_barrier(0) so the compiler cannot re-serialize the chains.
__device__ __forceinline__ void dual_step(float xpA, float xpB, St& A, St& B,
                                          const Ctx& k) {
    // G1: h quad-broadcasts + gate preactivation trees (A then B, independent)
    float a0 = dpp_f<0x00>(A.h), a1 = dpp_f<0x55>(A.h);
    float a2 = dpp_f<0xAA>(A.h), a3 = dpp_f<0xFF>(A.h);
    float b0 = dpp_f<0x00>(B.h), b1 = dpp_f<0x55>(B.h);
    float b2 = dpp_f<0xAA>(B.h), b3 = dpp_f<0xFF>(B.h);
    float pA0 = fmaf(a1, k.whh1, fmaf(a0, k.whh0, xpA));
    float pA1 = fmaf(a2, k.whh2, a3 * k.whh3);
    float gpA = pA0 + pA1;
    float pB0 = fmaf(b1, k.whh1, fmaf(b0, k.whh0, xpB));
    float pB1 = fmaf(b2, k.whh2, b3 * k.whh3);
    float gpB = pB0 + pB1;
    sb();
    // G2: gate exp2 (latency of A's covered by B issue + next wall's stall)
    float eA = __builtin_amdgcn_exp2f(gpA);
    float eB = __builtin_amdgcn_exp2f(gpB);
    sb();
    // G3: 1+e and rcp; A stalls ~20cy on eA, B's operand lands during it
    float dA = 1.0f + eA;
    float dB = 1.0f + eB;
    float rA = __builtin_amdgcn_rcpf(dA);
    float rB = __builtin_amdgcn_rcpf(dB);
    sb();
    // G4: affine to activation + gate rotations
    float actA = fmaf(k.Aa, rA, k.Bb);
    float actB = fmaf(k.Aa, rB, k.Bb);
    float tA1 = dpp_f<0x124>(actA), tA2 = dpp_f<0x128>(actA), tA3 = dpp_f<0x12C>(actA);
    float tB1 = dpp_f<0x124>(actB), tB2 = dpp_f<0x128>(actB), tB3 = dpp_f<0x12C>(actB);
    sb();
    // G5: gate muxes + c update + tanh argument
    float prodA = k.b0 ? tA1 * tA3 : actA * tA2;
    float selA1 = k.b0 ? tA2 : tA1;
    float selA2 = k.b0 ? actA : tA3;
    float fA = k.b1fo ? selA1 : selA2;
    float oA = k.b1fo ? selA2 : selA1;
    float prodB = k.b0 ? tB1 * tB3 : actB * tB2;
    float selB1 = k.b0 ? tB2 : tB1;
    float selB2 = k.b0 ? actB : tB3;
    float fB = k.b1fo ? selB1 : selB2;
    float oB = k.b1fo ? selB2 : selB1;
    float cnA = fmaf(fA, A.c, prodA); A.c = cnA;
    float cnB = fmaf(fB, B.c, prodB); B.c = cnB;
    float gA = -2.885390081777927f * cnA;
    float gB = -2.885390081777927f * cnB;
    sb();
    // G6: tanh exp2
    float e2A = __builtin_amdgcn_exp2f(gA);
    float e2B = __builtin_amdgcn_exp2f(gB);
    sb();
    // G7: 1+e2 and rcp
    float d2A = 1.0f + e2A;
    float d2B = 1.0f + e2B;
    float r2A = __builtin_amdgcn_rcpf(d2A);
    float r2B = __builtin_amdgcn_rcpf(d2B);
    sb();
    // G8: tanh affine + h
    float thA = fmaf(2.0f, r2A, -1.0f);
    float thB = fmaf(2.0f, r2B, -1.0f);
    A.h = oA * thA;
    B.h = oB * thB;
    sb();
}

template<int TT>
__device__ __forceinline__ void steps8_dual(const float (&xpA)[CHUNK],
                                            const float (&xpB)[CHUNK],
                                            St& A, St& B, const Ctx& k) {
    dual_step(xpA[TT], xpB[TT], A, B, k);
    if constexpr (TT + 1 < CHUNK) steps8_dual<TT + 1>(xpA, xpB, A, B, k);
}

__device__ __forceinline__ void load6(float4 (&bf)[6], const float4* p) {
    #pragma unroll
    for (int i = 0; i < 6; ++i) bf[i] = p[i];
}

__global__ __launch_bounds__(256, 1) void lstm_kernel(
    const float* __restrict__ x,
    const float* __restrict__ w_ih,
    const float* __restrict__ w_hh,
    const float* __restrict__ fc_w,
    const float* __restrict__ fc_b,
    float* __restrict__ out)
{
    const int tid = threadIdx.x;
    const int l16 = tid & 15;
    const int pr  = blockIdx.x * 16 + (tid >> 4);  // pair index 0..2047
    const int bA  = 2 * pr, bB = 2 * pr + 1;
    const int gt  = l16 >> 2;

    const bool is_g = (gt == 2);
    const float mm  = is_g ? -2.885390081777927f : -1.4426950408889634f;

    Ctx k;
    k.wih0 = mm * w_ih[l16 * 3 + 0];
    k.wih1 = mm * w_ih[l16 * 3 + 1];
    k.wih2 = mm * w_ih[l16 * 3 + 2];
    k.whh0 = mm * w_hh[l16 * 4 + 0];
    k.whh1 = mm * w_hh[l16 * 4 + 1];
    k.whh2 = mm * w_hh[l16 * 4 + 2];
    k.whh3 = mm * w_hh[l16 * 4 + 3];
    k.Aa = is_g ? 2.0f : 1.0f;
    k.Bb = is_g ? -1.0f : 0.0f;
    k.b0 = (gt & 1) != 0;
    {   // runtime probe for row_ror direction; folds into the f/o mux bit
        float probe = (float)l16;
        float t1p = dpp_f<0x124>(probe);
        bool dirB = (t1p == (float)((l16 + 4) & 15));
        k.b1fo = (((gt & 2) != 0) != dirB);
    }

    const float4* pA = reinterpret_cast<const float4*>(x + (size_t)bA * (T_STEPS * 3));
    const float4* pB = reinterpret_cast<const float4*>(x + (size_t)bB * (T_STEPS * 3));

    float4 fA0[6], fA1[6], fB0[6], fB1[6];
    float  xpAc[CHUNK], xpAn[CHUNK], xpBc[CHUNK], xpBn[CHUNK];

    load6(fA0, pA);      load6(fB0, pB);       // chunk 0
    load6(fA1, pA + 6);  load6(fB1, pB + 6);   // chunk 1
    pA += 12; pB += 12;
    projx8<0>(xpAc, fA0, k);
    projx8<0>(xpBc, fB0, k);

    St A{0.f, 0.f}, B{0.f, 0.f};

    for (int it = 0; it < NCHUNK / 2 - 1; ++it) {
        load6(fA0, pA); load6(fB0, pB); pA += 6; pB += 6;   // chunk 2it+2
        projx8<0>(xpAn, fA1, k);                             // chunk 2it+1
        projx8<0>(xpBn, fB1, k);
        steps8_dual<0>(xpAc, xpBc, A, B, k);                 // chunk 2it

        load6(fA1, pA); load6(fB1, pB); pA += 6; pB += 6;   // chunk 2it+3
        projx8<0>(xpAc, fA0, k);                             // chunk 2it+2
        projx8<0>(xpBc, fB0, k);
        steps8_dual<0>(xpAn, xpBn, A, B, k);                 // chunk 2it+1
    }
    // tail: chunks 254, 255 (already loaded)
    projx8<0>(xpAn, fA1, k);
    projx8<0>(xpBn, fB1, k);
    steps8_dual<0>(xpAc, xpBc, A, B, k);
    steps8_dual<0>(xpAn, xpBn, A, B, k);

    // out[b] = fc_w . h + fc_b ; lane 4m+j holds h_j -> quad reduce
    const float fw = fc_w[l16 & 3];
    float rA = A.h * fw;
    rA += dpp_f<0xB1>(rA);
    rA += dpp_f<0x4E>(rA);
    float rB = B.h * fw;
    rB += dpp_f<0xB1>(rB);
    rB += dpp_f<0x4E>(rB);
    if (l16 == 0) {
        const float fcb = fc_b[0];
        out[bA] = rA + fcb;
        out[bB] = rB + fcb;
    }
}

extern "C" void kernel_launch(void* const* d_in, const int* in_sizes, int n_in,
                              void* d_out, int out_size, void* d_ws, size_t ws_size,
                              hipStream_t stream) {
    const float* x    = (const float*)d_in[0];
    const float* w_ih = (const float*)d_in[1];
    const float* w_hh = (const float*)d_in[2];
    const float* fc_w = (const float*)d_in[3];
    const float* fc_b = (const float*)d_in[4];
    float* out = (float*)d_out;

    dim3 grid(4096 / 32);   // 128 blocks: 16 groups/block x 2 elems/group
    dim3 block(256);
    hipLaunchKernelGGL(lstm_kernel, grid, block, 0, stream,
                       x, w_ih, w_hh, fc_w, fc_b, out);
}